// Round 7
// baseline (148.836 us; speedup 1.0000x reference)
//
#include <hip/hip_runtime.h>
#include <hip/hip_bf16.h>
#include <stdint.h>

#define HID 1024
#define BLKDIM 128
#define BKT 32              // K-tile depth
#define NKT (HID / BKT)     // 32 K-tiles
#define NBUF 3              // triple buffer: depth-2 prefetch

using short8 = __attribute__((ext_vector_type(8))) short;
using f32x4  = __attribute__((ext_vector_type(4))) float;
using f32x4v = __attribute__((ext_vector_type(4))) float;
using u32x4v = __attribute__((ext_vector_type(4))) unsigned int;

__device__ __forceinline__ uint32_t bfround(float f) {
    uint32_t u = __builtin_bit_cast(uint32_t, f);
    return (u + 0x7FFFu + ((u >> 16) & 1u)) >> 16;   // RNE to bf16
}

__device__ __forceinline__ void gld16(const ushort* g, const ushort* lds_base) {
    // async global->LDS: per-lane global src, LDS dest = uniform base + lane*16
    __builtin_amdgcn_global_load_lds(
        (const __attribute__((address_space(1))) void*)g,
        (__attribute__((address_space(3))) void*)lds_base, 16, 0, 0);
}

// ---------------- pre-pass: fp32 -> bf16, 8 elems/thread ----------------
// fp32 source is read exactly once -> nontemporal loads (don't pollute L3).
// bf16 destination is the GEMM's operand -> normal (cacheable) stores.
__global__ __launch_bounds__(256)
void cvt_bf16_kernel(const float* __restrict__ src, uint4* __restrict__ dst, int n8) {
    int i = blockIdx.x * blockDim.x + threadIdx.x;
    if (i >= n8) return;
    const f32x4v* s = reinterpret_cast<const f32x4v*>(src) + (size_t)i * 2;
    f32x4v v0 = __builtin_nontemporal_load(s);
    f32x4v v1 = __builtin_nontemporal_load(s + 1);
    uint4 w;
    w.x = bfround(v0.x) | (bfround(v0.y) << 16);
    w.y = bfround(v0.z) | (bfround(v0.w) << 16);
    w.z = bfround(v1.x) | (bfround(v1.y) << 16);
    w.w = bfround(v1.z) | (bfround(v1.w) << 16);
    dst[i] = w;
}

// ---------------- main GEMM: 128x256 tile, BK=32, counted-vmcnt pipeline, 72 KB LDS ----------------
// LDS layout: row-pairs packed into 128-B super-rows.
//   phys_slot(row, slot4) = (slot4 + 4*(row&1)) ^ ((row>>1)&7)
//   addr_ushort(row, slot4) = (row>>1)*64 + phys_slot*8
// Write side: linear global_load_lds dest + inverse-permuted per-lane global source.
// Output stores are nontemporal: written once, never re-read by this kernel ->
// keep L3 for the 80 MB bf16 operand set.
__global__ __launch_bounds__(512, 4)
void sdd_pipe2_kernel(const ushort* __restrict__ xb, const ushort* __restrict__ wb,
                      const int* __restrict__ rind, const int* __restrict__ cind,
                      float* __restrict__ out) {
    __shared__ ushort sA[NBUF][BLKDIM * BKT];       // 3 x 8 KB
    __shared__ ushort sB[NBUF][2 * BLKDIM * BKT];   // 3 x 16 KB   (total 72 KB)

    int g = blockIdx.x;
    const int nwg = gridDim.x;
    if ((nwg & 7) == 0) {                 // bijective XCD swizzle
        const int cpx = nwg >> 3;
        g = (g & 7) * cpx + (g >> 3);
    }
    const int k0 = g * 2;
    const int r  = rind[k0];

    const int t = threadIdx.x;
    const int w = t >> 6;                 // wave 0..7
    const int l = t & 63;

    // ---- staging role: lane -> (row_in_16, slot4) via inverse of phys layout ----
    const int unx   = (l & 7) ^ ((l >> 3) & 7);
    const int rin16 = 2 * (l >> 3) + (unx >> 2);
    const int kofs  = (unx & 3) * 8;      // ushort offset within the 32-wide K-tile

    // A: wave w stages rows w*16 .. w*16+15 (1 issue)
    const ushort* agb = xb + (size_t)(r * BLKDIM + w * 16 + rin16) * HID + kofs;
    // B: wave w stages panel rows 32w..32w+31 (2 issues of 16 rows), one column-block
    const int cblk = cind[k0 + (w >> 2)];
    const ushort* bgb = wb + (size_t)(cblk * BLKDIM + (w & 3) * 32 + rin16) * HID + kofs;

    // ---- compute role: 8 waves as 2(M) x 4(N), each 64x64 ----
    const int wr   = (w >> 2) * 64;
    const int wcol = (w & 3) * 64;
    const int ps_l = (((l >> 4) + ((l & 1) << 2)) ^ ((l & 15) >> 1)) * 8;  // ushort offset
    const int rhalf = (l & 15) >> 1;

    int aoff[4], boff[4];
#pragma unroll
    for (int m = 0; m < 4; ++m) aoff[m] = (wr / 2 + m * 8 + rhalf) * 64 + ps_l;
#pragma unroll
    for (int n = 0; n < 4; ++n) boff[n] = (wcol / 2 + n * 8 + rhalf) * 64 + ps_l;

    f32x4 acc[4][4];
#pragma unroll
    for (int m = 0; m < 4; ++m)
#pragma unroll
        for (int n = 0; n < 4; ++n)
            acc[m][n] = (f32x4){0.f, 0.f, 0.f, 0.f};

    auto stage = [&](int b, int kt) {
        gld16(agb + kt * BKT, &sA[b][w * 512]);
        gld16(bgb + kt * BKT,                      &sB[b][(2 * w) * 512]);
        gld16(bgb + (size_t)16 * HID + kt * BKT,   &sB[b][(2 * w + 1) * 512]);
    };

    // ---- prologue: fill tiles 0 and 1 ----
    stage(0, 0);
    stage(1, 1);
    asm volatile("s_waitcnt vmcnt(3)" ::: "memory");   // tile 0 resident
    __builtin_amdgcn_s_barrier();
    __builtin_amdgcn_sched_barrier(0);

    for (int kt = 0; kt < NKT; ++kt) {
        const int cur = kt % 3;
        const int nxt = (kt + 2) % 3;
        const bool pre = (kt + 2) < NKT;
        const ushort* sa = &sA[cur][0];
        const ushort* sb = &sB[cur][0];

        // issue next-next tile's loads FIRST: maximum latency-hiding lead
        if (pre) stage(nxt, kt + 2);

        short8 aF[4], bF[4];
#pragma unroll
        for (int m = 0; m < 4; ++m)
            aF[m] = *reinterpret_cast<const short8*>(&sa[aoff[m]]);
#pragma unroll
        for (int n = 0; n < 4; ++n)
            bF[n] = *reinterpret_cast<const short8*>(&sb[boff[n]]);
        __builtin_amdgcn_s_setprio(1);
#pragma unroll
        for (int m = 0; m < 4; ++m)
#pragma unroll
            for (int n = 0; n < 4; ++n)
                acc[m][n] = __builtin_amdgcn_mfma_f32_16x16x32_bf16(aF[m], bF[n], acc[m][n], 0, 0, 0);
        __builtin_amdgcn_s_setprio(0);

        // tile boundary: counted drain (never 0 in steady state)
        if (pre) asm volatile("s_waitcnt vmcnt(3)" ::: "memory");
        else     asm volatile("s_waitcnt vmcnt(0)" ::: "memory");
        __builtin_amdgcn_s_barrier();
        __builtin_amdgcn_sched_barrier(0);
    }

    // ---- epilogue: C/D mapping col=lane&15, row=(lane>>4)*4+j ; nontemporal stores ----
    const int blk = (w & 3) >> 1;
    float* op = out + (size_t)(k0 + blk) * (BLKDIM * BLKDIM);
    const int colbase = (wcol & 64) ? 64 : 0;
    const int lr = l & 15;
    const int rbase = wr + (l >> 4) * 4;
#pragma unroll
    for (int m = 0; m < 4; ++m)
#pragma unroll
        for (int n = 0; n < 4; ++n) {
            const int col = colbase + n * 16 + lr;
#pragma unroll
            for (int j = 0; j < 4; ++j)
                __builtin_nontemporal_store(acc[m][n][j],
                    &op[(size_t)(rbase + m * 16 + j) * BLKDIM + col]);
        }
}

// ---------------- fallback (validated round-1 kernel) ----------------
__device__ __forceinline__ void store16f(ushort* dst, float4 v0, float4 v1, float4 v2, float4 v3) {
    uint4 w0, w1;
    w0.x = bfround(v0.x) | (bfround(v0.y) << 16);
    w0.y = bfround(v0.z) | (bfround(v0.w) << 16);
    w0.z = bfround(v1.x) | (bfround(v1.y) << 16);
    w0.w = bfround(v1.z) | (bfround(v1.w) << 16);
    w1.x = bfround(v2.x) | (bfround(v2.y) << 16);
    w1.y = bfround(v2.z) | (bfround(v2.w) << 16);
    w1.z = bfround(v3.x) | (bfround(v3.y) << 16);
    w1.w = bfround(v3.z) | (bfround(v3.w) << 16);
    uint4* d = reinterpret_cast<uint4*>(dst);
    d[0] = w0; d[1] = w1;
}

__global__ __launch_bounds__(256, 2)
void sdd_bf16_kernel(const float* __restrict__ x, const float* __restrict__ w1,
                     const int* __restrict__ rind, const int* __restrict__ cind,
                     float* __restrict__ out) {
    __shared__ ushort sA[2][BLKDIM * 32];
    __shared__ ushort sB[2][BLKDIM * 32];
    const int k = blockIdx.x;
    const int t = threadIdx.x;
    const int r = rind[k];
    const int c = cind[k];
    const float* Abase = x  + (size_t)r * BLKDIM * HID;
    const float* Bbase = w1 + (size_t)c * BLKDIM * HID;
    const int srow = t >> 1, shalf = t & 1;
    const float* aptr = Abase + (size_t)srow * HID + shalf * 16;
    const float* bptr = Bbase + (size_t)srow * HID + shalf * 16;
    const int soff = srow * 32 + shalf * 16;
    const int wv = t >> 6, lane = t & 63;
    const int wr = (wv >> 1) * 64, wc = (wv & 1) * 64;
    const int lr = lane & 15, lk = (lane >> 4) * 8;
    f32x4 acc[4][4];
#pragma unroll
    for (int m = 0; m < 4; ++m)
#pragma unroll
        for (int n = 0; n < 4; ++n) acc[m][n] = (f32x4){0.f, 0.f, 0.f, 0.f};
    float4 ra[4], rb[4];
#pragma unroll
    for (int i = 0; i < 4; ++i) {
        ra[i] = *reinterpret_cast<const float4*>(aptr + i * 4);
        rb[i] = *reinterpret_cast<const float4*>(bptr + i * 4);
    }
    store16f(&sA[0][soff], ra[0], ra[1], ra[2], ra[3]);
    store16f(&sB[0][soff], rb[0], rb[1], rb[2], rb[3]);
    __syncthreads();
    for (int kt = 0; kt < 32; ++kt) {
        const int cur = kt & 1;
        if (kt + 1 < 32) {
            const float* ap = aptr + (kt + 1) * 32;
            const float* bp = bptr + (kt + 1) * 32;
#pragma unroll
            for (int i = 0; i < 4; ++i) {
                ra[i] = *reinterpret_cast<const float4*>(ap + i * 4);
                rb[i] = *reinterpret_cast<const float4*>(bp + i * 4);
            }
        }
        const ushort* sa = sA[cur];
        const ushort* sb = sB[cur];
        short8 aF[4], bF[4];
#pragma unroll
        for (int m = 0; m < 4; ++m) aF[m] = *reinterpret_cast<const short8*>(&sa[(wr + m * 16 + lr) * 32 + lk]);
#pragma unroll
        for (int n = 0; n < 4; ++n) bF[n] = *reinterpret_cast<const short8*>(&sb[(wc + n * 16 + lr) * 32 + lk]);
#pragma unroll
        for (int m = 0; m < 4; ++m)
#pragma unroll
            for (int n = 0; n < 4; ++n)
                acc[m][n] = __builtin_amdgcn_mfma_f32_16x16x32_bf16(aF[m], bF[n], acc[m][n], 0, 0, 0);
        if (kt + 1 < 32) {
            store16f(&sA[cur ^ 1][soff], ra[0], ra[1], ra[2], ra[3]);
            store16f(&sB[cur ^ 1][soff], rb[0], rb[1], rb[2], rb[3]);
        }
        __syncthreads();
    }
    float* op = out + (size_t)k * (BLKDIM * BLKDIM);
    const int rbase = wr + (lane >> 4) * 4;
#pragma unroll
    for (int m = 0; m < 4; ++m)
#pragma unroll
        for (int n = 0; n < 4; ++n) {
            const int col = wc + n * 16 + lr;
#pragma unroll
            for (int j = 0; j < 4; ++j)
                op[(size_t)(rbase + m * 16 + j) * BLKDIM + col] = acc[m][n][j];
        }
}

extern "C" void kernel_launch(void* const* d_in, const int* in_sizes, int n_in,
                              void* d_out, int out_size, void* d_ws, size_t ws_size,
                              hipStream_t stream) {
    const float* x  = (const float*)d_in[0];
    const float* w1 = (const float*)d_in[1];
    const int* ri   = (const int*)d_in[2];
    const int* ci   = (const int*)d_in[3];
    float* out      = (float*)d_out;
    const int nnz   = in_sizes[2];
    const int nx    = in_sizes[0];
    const int nw    = in_sizes[1];

    const size_t need = ((size_t)nx + (size_t)nw) * sizeof(ushort);
    if (ws_size >= need && (nnz & 1) == 0) {
        ushort* xb = (ushort*)d_ws;
        ushort* wb = xb + nx;
        const int nx8 = nx / 8, nw8 = nw / 8;
        hipLaunchKernelGGL(cvt_bf16_kernel, dim3((nx8 + 255) / 256), dim3(256), 0, stream,
                           x, (uint4*)xb, nx8);
        hipLaunchKernelGGL(cvt_bf16_kernel, dim3((nw8 + 255) / 256), dim3(256), 0, stream,
                           w1, (uint4*)wb, nw8);
        hipLaunchKernelGGL(sdd_pipe2_kernel, dim3(nnz / 2), dim3(512), 0, stream,
                           xb, wb, ri, ci, out);
    } else {
        hipLaunchKernelGGL(sdd_bf16_kernel, dim3(nnz), dim3(256), 0, stream,
                           x, w1, ri, ci, out);
    }
}

// Round 8
// 141.176 us; speedup vs baseline: 1.0543x; 1.0543x over previous
//
#include <hip/hip_runtime.h>
#include <hip/hip_bf16.h>
#include <stdint.h>

#define HID 1024
#define BLKDIM 128
#define BKT 32              // K-tile depth
#define NKT (HID / BKT)     // 32 K-tiles
#define NBUF 3              // triple buffer: depth-2 prefetch

using short8 = __attribute__((ext_vector_type(8))) short;
using f32x4  = __attribute__((ext_vector_type(4))) float;
using f32x4v = __attribute__((ext_vector_type(4))) float;

__device__ __forceinline__ uint32_t bfround(float f) {
    uint32_t u = __builtin_bit_cast(uint32_t, f);
    return (u + 0x7FFFu + ((u >> 16) & 1u)) >> 16;   // RNE to bf16
}

__device__ __forceinline__ void gld16(const ushort* g, const ushort* lds_base) {
    // async global->LDS: per-lane global src, LDS dest = uniform base + lane*16
    __builtin_amdgcn_global_load_lds(
        (const __attribute__((address_space(1))) void*)g,
        (__attribute__((address_space(3))) void*)lds_base, 16, 0, 0);
}

// ---------------- pre-pass: fp32 -> bf16, 8 elems/thread ----------------
// fp32 source read exactly once -> nontemporal loads (keep caches for operands).
// bf16 destination is the GEMM's operand -> normal (cacheable) stores.
__global__ __launch_bounds__(256)
void cvt_bf16_kernel(const float* __restrict__ src, uint4* __restrict__ dst, int n8) {
    int i = blockIdx.x * blockDim.x + threadIdx.x;
    if (i >= n8) return;
    const f32x4v* s = reinterpret_cast<const f32x4v*>(src) + (size_t)i * 2;
    f32x4v v0 = __builtin_nontemporal_load(s);
    f32x4v v1 = __builtin_nontemporal_load(s + 1);
    uint4 w;
    w.x = bfround(v0.x) | (bfround(v0.y) << 16);
    w.y = bfround(v0.z) | (bfround(v0.w) << 16);
    w.z = bfround(v1.x) | (bfround(v1.y) << 16);
    w.w = bfround(v1.z) | (bfround(v1.w) << 16);
    dst[i] = w;
}

// ---------------- main GEMM: 128x256 tile, BK=32, counted-vmcnt pipeline, 72 KB LDS ----------------
// LDS layout: row-pairs packed into 128-B super-rows.
//   phys_slot(row, slot4) = (slot4 + 4*(row&1)) ^ ((row>>1)&7)
//   addr_ushort(row, slot4) = (row>>1)*64 + phys_slot*8
// Write side: linear global_load_lds dest + inverse-permuted per-lane global source.
// Epilogue: per-wave LDS transpose -> float4 FULL-LINE nontemporal stores
// (streams the 131 MB output past L2/MALL without partial-line amplification).
__global__ __launch_bounds__(512, 4)
void sdd_pipe2_kernel(const ushort* __restrict__ xb, const ushort* __restrict__ wb,
                      const int* __restrict__ rind, const int* __restrict__ cind,
                      float* __restrict__ out) {
    // one flat LDS block: staging buffers while looping, scratch for epilogue
    __shared__ ushort lds[NBUF * BLKDIM * BKT + NBUF * 2 * BLKDIM * BKT];  // 72 KB

    int g = blockIdx.x;
    const int nwg = gridDim.x;
    if ((nwg & 7) == 0) {                 // bijective XCD swizzle
        const int cpx = nwg >> 3;
        g = (g & 7) * cpx + (g >> 3);
    }
    const int k0 = g * 2;
    const int r  = rind[k0];

    const int t = threadIdx.x;
    const int w = t >> 6;                 // wave 0..7
    const int l = t & 63;

    ushort* sAb = lds;                            // NBUF x 4096 ushorts
    ushort* sBb = lds + NBUF * BLKDIM * BKT;      // NBUF x 8192 ushorts

    // ---- staging role: lane -> (row_in_16, slot4) via inverse of phys layout ----
    const int unx   = (l & 7) ^ ((l >> 3) & 7);
    const int rin16 = 2 * (l >> 3) + (unx >> 2);
    const int kofs  = (unx & 3) * 8;      // ushort offset within the 32-wide K-tile

    // A: wave w stages rows w*16 .. w*16+15 (1 issue)
    const ushort* agb = xb + (size_t)(r * BLKDIM + w * 16 + rin16) * HID + kofs;
    // B: wave w stages panel rows 32w..32w+31 (2 issues of 16 rows), one column-block
    const int cblk = cind[k0 + (w >> 2)];
    const ushort* bgb = wb + (size_t)(cblk * BLKDIM + (w & 3) * 32 + rin16) * HID + kofs;

    // ---- compute role: 8 waves as 2(M) x 4(N), each 64x64 ----
    const int wr   = (w >> 2) * 64;
    const int wcol = (w & 3) * 64;
    const int ps_l = (((l >> 4) + ((l & 1) << 2)) ^ ((l & 15) >> 1)) * 8;  // ushort offset
    const int rhalf = (l & 15) >> 1;

    int aoff[4], boff[4];
#pragma unroll
    for (int m = 0; m < 4; ++m) aoff[m] = (wr / 2 + m * 8 + rhalf) * 64 + ps_l;
#pragma unroll
    for (int n = 0; n < 4; ++n) boff[n] = (wcol / 2 + n * 8 + rhalf) * 64 + ps_l;

    f32x4 acc[4][4];
#pragma unroll
    for (int m = 0; m < 4; ++m)
#pragma unroll
        for (int n = 0; n < 4; ++n)
            acc[m][n] = (f32x4){0.f, 0.f, 0.f, 0.f};

    auto stage = [&](int b, int kt) {
        gld16(agb + kt * BKT, &sAb[b * 4096 + w * 512]);
        gld16(bgb + kt * BKT,                      &sBb[b * 8192 + (2 * w) * 512]);
        gld16(bgb + (size_t)16 * HID + kt * BKT,   &sBb[b * 8192 + (2 * w + 1) * 512]);
    };

    // ---- prologue: fill tiles 0 and 1 ----
    stage(0, 0);
    stage(1, 1);
    asm volatile("s_waitcnt vmcnt(3)" ::: "memory");   // tile 0 resident
    __builtin_amdgcn_s_barrier();
    __builtin_amdgcn_sched_barrier(0);

    for (int kt = 0; kt < NKT; ++kt) {
        const int cur = kt % 3;
        const int nxt = (kt + 2) % 3;
        const bool pre = (kt + 2) < NKT;
        const ushort* sa = &sAb[cur * 4096];
        const ushort* sb = &sBb[cur * 8192];

        short8 aF[4], bF[4];
#pragma unroll
        for (int m = 0; m < 4; ++m)
            aF[m] = *reinterpret_cast<const short8*>(&sa[aoff[m]]);
#pragma unroll
        for (int n = 0; n < 4; ++n)
            bF[n] = *reinterpret_cast<const short8*>(&sb[boff[n]]);
        if (pre) stage(nxt, kt + 2);
        __builtin_amdgcn_s_setprio(1);
#pragma unroll
        for (int m = 0; m < 4; ++m)
#pragma unroll
            for (int n = 0; n < 4; ++n)
                acc[m][n] = __builtin_amdgcn_mfma_f32_16x16x32_bf16(aF[m], bF[n], acc[m][n], 0, 0, 0);
        __builtin_amdgcn_s_setprio(0);

        // tile boundary: counted drain (never 0 in steady state)
        if (pre) asm volatile("s_waitcnt vmcnt(3)" ::: "memory");
        else     asm volatile("s_waitcnt vmcnt(0)" ::: "memory");
        __builtin_amdgcn_s_barrier();
        __builtin_amdgcn_sched_barrier(0);
    }
    // final barrier passed: all staging LDS traffic complete -> safe to reuse as scratch

    // ---- epilogue: per-wave LDS transpose, then full-line nontemporal float4 stores ----
    // C/D mapping: col = lane&15 (per n*16), row = (lane>>4)*4 + j (per m*16).
    const int blk = (w & 3) >> 1;
    float* op = out + (size_t)(k0 + blk) * (BLKDIM * BLKDIM);
    const int colbase = (wcol & 64) ? 64 : 0;
    float* scr = reinterpret_cast<float*>(lds) + w * 1152;   // 16 rows x 72 floats per wave

#pragma unroll
    for (int m = 0; m < 4; ++m) {
        // scatter this 16x64 sub-tile into scratch (row-major, stride 72)
#pragma unroll
        for (int n = 0; n < 4; ++n)
#pragma unroll
            for (int j = 0; j < 4; ++j)
                scr[((l >> 4) * 4 + j) * 72 + n * 16 + (l & 15)] = acc[m][n][j];
        // gather: lane l -> row rg*4 + (l>>4), 4 consecutive cols (l&15)*4
#pragma unroll
        for (int rg = 0; rg < 4; ++rg) {
            const int tr = rg * 4 + (l >> 4);
            f32x4 v = *reinterpret_cast<const f32x4*>(&scr[tr * 72 + (l & 15) * 4]);
            __builtin_nontemporal_store(v,
                reinterpret_cast<f32x4*>(&op[(size_t)(wr + m * 16 + tr) * BLKDIM
                                             + colbase + (l & 15) * 4]));
        }
    }
}

// ---------------- fallback (validated round-1 kernel) ----------------
__device__ __forceinline__ void store16f(ushort* dst, float4 v0, float4 v1, float4 v2, float4 v3) {
    uint4 w0, w1;
    w0.x = bfround(v0.x) | (bfround(v0.y) << 16);
    w0.y = bfround(v0.z) | (bfround(v0.w) << 16);
    w0.z = bfround(v1.x) | (bfround(v1.y) << 16);
    w0.w = bfround(v1.z) | (bfround(v1.w) << 16);
    w1.x = bfround(v2.x) | (bfround(v2.y) << 16);
    w1.y = bfround(v2.z) | (bfround(v2.w) << 16);
    w1.z = bfround(v3.x) | (bfround(v3.y) << 16);
    w1.w = bfround(v3.z) | (bfround(v3.w) << 16);
    uint4* d = reinterpret_cast<uint4*>(dst);
    d[0] = w0; d[1] = w1;
}

__global__ __launch_bounds__(256, 2)
void sdd_bf16_kernel(const float* __restrict__ x, const float* __restrict__ w1,
                     const int* __restrict__ rind, const int* __restrict__ cind,
                     float* __restrict__ out) {
    __shared__ ushort sA[2][BLKDIM * 32];
    __shared__ ushort sB[2][BLKDIM * 32];
    const int k = blockIdx.x;
    const int t = threadIdx.x;
    const int r = rind[k];
    const int c = cind[k];
    const float* Abase = x  + (size_t)r * BLKDIM * HID;
    const float* Bbase = w1 + (size_t)c * BLKDIM * HID;
    const int srow = t >> 1, shalf = t & 1;
    const float* aptr = Abase + (size_t)srow * HID + shalf * 16;
    const float* bptr = Bbase + (size_t)srow * HID + shalf * 16;
    const int soff = srow * 32 + shalf * 16;
    const int wv = t >> 6, lane = t & 63;
    const int wr = (wv >> 1) * 64, wc = (wv & 1) * 64;
    const int lr = lane & 15, lk = (lane >> 4) * 8;
    f32x4 acc[4][4];
#pragma unroll
    for (int m = 0; m < 4; ++m)
#pragma unroll
        for (int n = 0; n < 4; ++n) acc[m][n] = (f32x4){0.f, 0.f, 0.f, 0.f};
    float4 ra[4], rb[4];
#pragma unroll
    for (int i = 0; i < 4; ++i) {
        ra[i] = *reinterpret_cast<const float4*>(aptr + i * 4);
        rb[i] = *reinterpret_cast<const float4*>(bptr + i * 4);
    }
    store16f(&sA[0][soff], ra[0], ra[1], ra[2], ra[3]);
    store16f(&sB[0][soff], rb[0], rb[1], rb[2], rb[3]);
    __syncthreads();
    for (int kt = 0; kt < 32; ++kt) {
        const int cur = kt & 1;
        if (kt + 1 < 32) {
            const float* ap = aptr + (kt + 1) * 32;
            const float* bp = bptr + (kt + 1) * 32;
#pragma unroll
            for (int i = 0; i < 4; ++i) {
                ra[i] = *reinterpret_cast<const float4*>(ap + i * 4);
                rb[i] = *reinterpret_cast<const float4*>(bp + i * 4);
            }
        }
        const ushort* sa = sA[cur];
        const ushort* sb = sB[cur];
        short8 aF[4], bF[4];
#pragma unroll
        for (int m = 0; m < 4; ++m) aF[m] = *reinterpret_cast<const short8*>(&sa[(wr + m * 16 + lr) * 32 + lk]);
#pragma unroll
        for (int n = 0; n < 4; ++n) bF[n] = *reinterpret_cast<const short8*>(&sb[(wc + n * 16 + lr) * 32 + lk]);
#pragma unroll
        for (int m = 0; m < 4; ++m)
#pragma unroll
            for (int n = 0; n < 4; ++n)
                acc[m][n] = __builtin_amdgcn_mfma_f32_16x16x32_bf16(aF[m], bF[n], acc[m][n], 0, 0, 0);
        if (kt + 1 < 32) {
            store16f(&sA[cur ^ 1][soff], ra[0], ra[1], ra[2], ra[3]);
            store16f(&sB[cur ^ 1][soff], rb[0], rb[1], rb[2], rb[3]);
        }
        __syncthreads();
    }
    float* op = out + (size_t)k * (BLKDIM * BLKDIM);
    const int rbase = wr + (lane >> 4) * 4;
#pragma unroll
    for (int m = 0; m < 4; ++m)
#pragma unroll
        for (int n = 0; n < 4; ++n) {
            const int col = wc + n * 16 + lr;
#pragma unroll
            for (int j = 0; j < 4; ++j)
                op[(size_t)(rbase + m * 16 + j) * BLKDIM + col] = acc[m][n][j];
        }
}

extern "C" void kernel_launch(void* const* d_in, const int* in_sizes, int n_in,
                              void* d_out, int out_size, void* d_ws, size_t ws_size,
                              hipStream_t stream) {
    const float* x  = (const float*)d_in[0];
    const float* w1 = (const float*)d_in[1];
    const int* ri   = (const int*)d_in[2];
    const int* ci   = (const int*)d_in[3];
    float* out      = (float*)d_out;
    const int nnz   = in_sizes[2];
    const int nx    = in_sizes[0];
    const int nw    = in_sizes[1];

    const size_t need = ((size_t)nx + (size_t)nw) * sizeof(ushort);
    if (ws_size >= need && (nnz & 1) == 0) {
        ushort* xb = (ushort*)d_ws;
        ushort* wb = xb + nx;
        const int nx8 = nx / 8, nw8 = nw / 8;
        hipLaunchKernelGGL(cvt_bf16_kernel, dim3((nx8 + 255) / 256), dim3(256), 0, stream,
                           x, (uint4*)xb, nx8);
        hipLaunchKernelGGL(cvt_bf16_kernel, dim3((nw8 + 255) / 256), dim3(256), 0, stream,
                           w1, (uint4*)wb, nw8);
        hipLaunchKernelGGL(sdd_pipe2_kernel, dim3(nnz / 2), dim3(512), 0, stream,
                           xb, wb, ri, ci, out);
    } else {
        hipLaunchKernelGGL(sdd_bf16_kernel, dim3(nnz), dim3(256), 0, stream,
                           x, w1, ri, ci, out);
    }
}